// Round 4
// baseline (6801.841 us; speedup 1.0000x reference)
//
#include <hip/hip_runtime.h>
#include <hip/hip_bf16.h>
#include <hip/hip_fp16.h>

// GCN 3-layer. R13: agg with GUARANTEED XCD-L2 residency. R12 post-mortem:
// blockIdx%8->XCD round-robin assumption failed (FETCH rose, no residency) and
// per-wave MLP collapsed (4.8 B/cyc/CU == 40 segs in flight, matching the
// queue*latency model). R13: each block reads its PHYSICAL XCD id via
// s_getreg(HW_REG_XCC_ID) [HW-verified gfx950] and serves feature-chunk
// xcd&(NCH-1); nodes handed out by per-chunk global atomic counters (work-
// stealing, no mapping assumption; steals other chunks after own drains so
// correctness never depends on XCC_ID). Per-XCD gather slice = 50000x64B =
// 3.2MB < 4MB L2 -> ~200cy hits. MLP kept at R10 level: 4 edges x 16 lanes x
// half2 per instr (4 segs), UNC=6 in flight (24 edges), ep prefetched one
// group ahead (nontemporal, 1 seg/instr), tail clamped to end-1 (waste
// coalesces). CSR build + MFMA gemms + fused val/wt passes unchanged.

#define K_IN 128              // all layers have in_features == 128
#define FIX_SCALE 8388608.0f  // 2^23 fixed point for ew sums
#define CE 4096               // edges per partition block (1024 thr x 4)

typedef _Float16 f16x8 __attribute__((ext_vector_type(8)));
typedef float f32x4 __attribute__((ext_vector_type(4)));

// ---------- pass 1: per-block bucket histogram + local rank (+W prep tail) ----------
__global__ __launch_bounds__(1024) void part_count_wt(
    const int* __restrict__ dst, int* __restrict__ counts,
    unsigned short* __restrict__ lrank, int nb, int nblk, int e,
    const float* __restrict__ W1, const float* __restrict__ W2,
    const float* __restrict__ W3, _Float16* __restrict__ Wt1,
    _Float16* __restrict__ Wt2, _Float16* __restrict__ Wt3,
    int* __restrict__ ctr) {
    int blk = blockIdx.x;
    if (blk >= nblk) {  // tail blocks: Wt[n][k] fp16 = W[k][n] fp32
        if (blk == nblk && threadIdx.x < 24) ctr[threadIdx.x] = 0;  // agg counters
        int i = (blk - nblk) * 1024 + threadIdx.x;
        if (i < 128 * 128) {
            int k = i >> 7, nn = i & 127;
            Wt1[(size_t)nn * 128 + k] = (_Float16)W1[i];
        } else if (i < 2 * 128 * 128) {
            int j = i - 128 * 128, k = j >> 7, nn = j & 127;
            Wt2[(size_t)nn * 128 + k] = (_Float16)W2[j];
        } else if (i < 2 * 128 * 128 + 64 * 128) {
            int l = i - 2 * 128 * 128, k = l >> 6, nn = l & 63;
            Wt3[(size_t)nn * 128 + k] = (_Float16)W3[l];
        }
        return;
    }
    __shared__ int c[256];  // nb <= 256
    int t = threadIdx.x;
    for (int i = t; i < nb; i += 1024) c[i] = 0;
    __syncthreads();
    int b0 = blk * CE;
#pragma unroll
    for (int j = 0; j < 4; j++) {
        int i = b0 + j * 1024 + t;
        if (i < e) {
            int b = dst[i] >> 8;
            int r = atomicAdd(&c[b], 1);  // LDS atomic
            lrank[i] = (unsigned short)r;
        }
    }
    __syncthreads();
    for (int i = t; i < nb; i += 1024) counts[(size_t)i * nblk + blk] = c[i];
}

// ---------- pass 2: parallel exclusive scan over counts[nb*nblk] ----------
__global__ __launch_bounds__(256) void reduce_kernel(const int* __restrict__ v,
                                                     int* __restrict__ bs, int m) {
    __shared__ int s[256];
    int t = threadIdx.x, i = blockIdx.x * 256 + t;
    s[t] = (i < m) ? v[i] : 0;
    __syncthreads();
    for (int off = 128; off > 0; off >>= 1) {
        if (t < off) s[t] += s[t + off];
        __syncthreads();
    }
    if (t == 0) bs[blockIdx.x] = s[0];
}

__global__ __launch_bounds__(1024) void scanb1024(const int* __restrict__ bs,
                                                  int* __restrict__ bo, int nbb) {
    __shared__ int s[1024];
    int t = threadIdx.x;
    s[t] = (t < nbb) ? bs[t] : 0;
    __syncthreads();
    for (int off = 1; off < 1024; off <<= 1) {
        int cur = s[t];
        int add = (t >= off) ? s[t - off] : 0;
        __syncthreads();
        s[t] = cur + add;
        __syncthreads();
    }
    if (t < nbb) bo[t] = (t == 0) ? 0 : s[t - 1];
}

__global__ __launch_bounds__(256) void scanw_kernel(const int* __restrict__ v,
                                                    const int* __restrict__ bo,
                                                    int* __restrict__ outp, int m) {
    __shared__ int s[256];
    int t = threadIdx.x, i = blockIdx.x * 256 + t;
    int c = (i < m) ? v[i] : 0;
    s[t] = c;
    __syncthreads();
    for (int off = 1; off < 256; off <<= 1) {
        int cur = s[t];
        int add = (t >= off) ? s[t - off] : 0;
        __syncthreads();
        s[t] = cur + add;
        __syncthreads();
    }
    if (i < m) outp[i] = bo[blockIdx.x] + (s[t] - c);  // exclusive
}

// ---------- pass 3: scatter into bucket-sorted order (packed src|dlow) ----------
__global__ __launch_bounds__(1024) void part_scatter(const int* __restrict__ src,
                                                     const int* __restrict__ dst,
                                                     const float* __restrict__ ew,
                                                     const int* __restrict__ base,
                                                     const unsigned short* __restrict__ lrank,
                                                     int2* __restrict__ arr1,
                                                     int nblk, int e) {
    int t = threadIdx.x, blk = blockIdx.x;
    int b0 = blk * CE;
#pragma unroll
    for (int j = 0; j < 4; j++) {
        int i = b0 + j * 1024 + t;
        if (i < e) {
            int d = dst[i];
            int b = d >> 8;
            int pos = base[(size_t)b * nblk + blk] + lrank[i];
            arr1[pos] = make_int2((src[i] << 8) | (d & 255), __float_as_int(ew[i]));
        }
    }
}

// ---------- pass 4: per-bucket CSR finalize (one 64-bit LDS atomic/edge) ----------
__global__ __launch_bounds__(1024) void bucket_csr(const int2* __restrict__ arr1,
                                                   const int* __restrict__ base,
                                                   unsigned short* __restrict__ rank2,
                                                   float* __restrict__ dinv,
                                                   int* __restrict__ row_ptr,
                                                   int2* __restrict__ ep,
                                                   int nb, int nblk, int n, int e) {
    __shared__ unsigned long long pk[256];  // cnt lo32 | fx-sum hi32
    __shared__ int nbase[256];
    __shared__ float ldsdinv[256];
    __shared__ int ss[256];
    int t = threadIdx.x, b = blockIdx.x;
    int beg = base[(size_t)b * nblk];
    int end = (b + 1 < nb) ? base[(size_t)(b + 1) * nblk] : e;
    if (t < 256) pk[t] = 0ULL;
    __syncthreads();
    for (int i = beg + t; i < end; i += 1024) {
        int2 a = arr1[i];
        int ld = a.x & 255;
        float w = __int_as_float(a.y);
        unsigned long long fx = (unsigned long long)(unsigned int)(w * FIX_SCALE + 0.5f);
        unsigned long long old = atomicAdd(&pk[ld], (fx << 32) | 1ULL);  // LDS, deterministic
        rank2[i] = (unsigned short)(old & 0xffffffffULL);
    }
    __syncthreads();
    int cnt = (t < 256) ? (int)(pk[t] & 0xffffffffULL) : 0;
    if (t < 256) ss[t] = cnt;
    __syncthreads();
    for (int off = 1; off < 256; off <<= 1) {
        int cur = 0, add = 0;
        if (t < 256) { cur = ss[t]; add = (t >= off) ? ss[t - off] : 0; }
        __syncthreads();
        if (t < 256) ss[t] = cur + add;
        __syncthreads();
    }
    if (t < 256) {
        nbase[t] = ss[t] - cnt;
        int d = b * 256 + t;
        if (d < n) {
            float dv = rsqrtf(1.0f + (float)(unsigned int)(pk[t] >> 32) * (1.0f / FIX_SCALE));
            dinv[d] = dv;
            ldsdinv[t] = dv;
            row_ptr[d] = beg + nbase[t];
        }
    }
    __syncthreads();
    for (int i = beg + t; i < end; i += 1024) {
        int2 a = arr1[i];
        int ld = a.x & 255;
        int pos = beg + nbase[ld] + rank2[i];
        float w = __int_as_float(a.y) * ldsdinv[ld];
        ep[pos] = make_int2(a.x >> 8, __float_as_int(w));  // src index, w*dinv[dst]
    }
}

// ---------- MFMA GEMM (+optional fused val pass in tail blocks) ----------
// H[n x NOUT](fp16) = X[n x 128] @ W. val: ep -> (src*256 byte off, w*dinv[src]).
template <int NOUT, bool XF16, bool FUSEVAL>
__global__ __launch_bounds__(256) void mfma_gemm(const void* __restrict__ Xv,
                                                 const _Float16* __restrict__ Wt,
                                                 _Float16* __restrict__ H, int n,
                                                 int gGemm, int vblk,
                                                 int2* __restrict__ ep,
                                                 const float* __restrict__ dinv,
                                                 int* __restrict__ row_ptr, int e) {
    constexpr int CTW = NOUT / 64;  // col-tiles per wave: 2 (NOUT=128) / 1 (64)
    __shared__ _Float16 Xs[64][136];   // +8 pad: row stride 272B -> 2-way banks
    __shared__ _Float16 Ws[NOUT][136];
    int t = threadIdx.x;
    if (FUSEVAL && (int)blockIdx.x >= gGemm) {  // tail blocks: val pass
        int vb = blockIdx.x - gGemm;
        if (vb == 0 && t == 0) row_ptr[n] = e;
        for (int i = vb * 256 + t; i < e; i += vblk * 256) {
            int2 a = ep[i];
            float w = __int_as_float(a.y) * dinv[a.x];
            ep[i] = make_int2(a.x << 8, __float_as_int(w));  // byte off (fp16 row F=128)
        }
        return;
    }
    int row0 = blockIdx.x * 64;

    for (int i = t * 8; i < NOUT * K_IN; i += 2048) {
        int nn = i >> 7, k = i & 127;
        *(uint4*)&Ws[nn][k] = *(const uint4*)&Wt[i];
    }
    if (XF16) {
        const _Float16* X = (const _Float16*)Xv;
        for (int i = t * 8; i < 64 * K_IN; i += 2048) {
            int r = i >> 7, k = i & 127;
            int row = row0 + r;
            uint4 v = make_uint4(0u, 0u, 0u, 0u);
            if (row < n) v = *(const uint4*)(X + (size_t)row * K_IN + k);
            *(uint4*)&Xs[r][k] = v;
        }
    } else {
        const float* X = (const float*)Xv;
        for (int i = t * 4; i < 64 * K_IN; i += 1024) {
            int r = i >> 7, k = i & 127;
            int row = row0 + r;
            float4 x4 = make_float4(0.f, 0.f, 0.f, 0.f);
            if (row < n) x4 = *(const float4*)(X + (size_t)row * K_IN + k);
            union { _Float16 h[4]; uint2 u; } uu;
            uu.h[0] = (_Float16)x4.x; uu.h[1] = (_Float16)x4.y;
            uu.h[2] = (_Float16)x4.z; uu.h[3] = (_Float16)x4.w;
            *(uint2*)&Xs[r][k] = uu.u;
        }
    }
    __syncthreads();

    int lane = t & 63, w = t >> 6;
    int m = lane & 15, g = lane >> 4;
    f32x4 acc[4][CTW];
#pragma unroll
    for (int mt = 0; mt < 4; mt++)
#pragma unroll
        for (int ct = 0; ct < CTW; ct++) acc[mt][ct] = (f32x4){0.f, 0.f, 0.f, 0.f};

#pragma unroll
    for (int kt = 0; kt < 4; kt++) {
        int kb = kt * 32 + g * 8;
        f16x8 a[4];
#pragma unroll
        for (int mt = 0; mt < 4; mt++) a[mt] = *(const f16x8*)&Xs[mt * 16 + m][kb];
#pragma unroll
        for (int ct = 0; ct < CTW; ct++) {
            int nn = w * (16 * CTW) + ct * 16 + m;
            f16x8 b = *(const f16x8*)&Ws[nn][kb];
#pragma unroll
            for (int mt = 0; mt < 4; mt++)
                acc[mt][ct] = __builtin_amdgcn_mfma_f32_16x16x32_f16(a[mt], b, acc[mt][ct], 0, 0, 0);
        }
    }

#pragma unroll
    for (int mt = 0; mt < 4; mt++) {
#pragma unroll
        for (int r = 0; r < 4; r++) {
            int row = row0 + mt * 16 + g * 4 + r;
            if (row < n) {
#pragma unroll
                for (int ct = 0; ct < CTW; ct++)
                    H[(size_t)row * NOUT + w * (16 * CTW) + ct * 16 + m] =
                        (_Float16)acc[mt][ct][r];
            }
        }
    }
}

// ---------- aggregation: XCC-pinned feature chunks + work-stealing ----------
// Block reads physical XCD id; serves chunk (xcd & NCH-1) -> per-XCD gather
// slice 3.2MB (L2-resident). Per-chunk atomic counters hand out nodes per
// wave; after own chunk drains, steal others (correct for any XCC_ID value).
// Lane layout: 4 edge slots x 16 lanes x half2 -> 4 segs/instr, UNC=6 deep.
template <int F, bool RELU, bool OF16>
__global__ __launch_bounds__(256) void agg_kernel(const __half* __restrict__ H,
                                                  const int* __restrict__ row_ptr,
                                                  const int2* __restrict__ ep,
                                                  const float* __restrict__ dinv,
                                                  const float* __restrict__ bias,
                                                  void* __restrict__ outv,
                                                  int* __restrict__ ctr, int n) {
    constexpr int NCH = (F == 128) ? 4 : 2;  // 64B feature chunks per fp16 row
    constexpr int UNC = 6;                   // 4-edge gather instrs in flight
    int lane = threadIdx.x & 63;
    int es = lane >> 4;          // edge slot 0..3
    int fl = lane & 15;          // half2 index within the 64B chunk
    unsigned xcd;
    asm volatile("s_getreg_b32 %0, hwreg(HW_REG_XCC_ID)" : "=s"(xcd));
    const char* Hb = (const char*)H;

    for (int ci = 0; ci < NCH; ci++) {  // own chunk first, then steal
        int chunk = ((int)xcd + ci) & (NCH - 1);
        const unsigned cb = (unsigned)chunk * 64u + (unsigned)fl * 4u;

        auto process = [&](int node) {
            int snode = __builtin_amdgcn_readfirstlane(node);
            int start = __builtin_amdgcn_readfirstlane(row_ptr[snode]);
            int end   = __builtin_amdgcn_readfirstlane(row_ptr[snode + 1]);
            float di = dinv[snode];
            float sw = di * di;

            float a0, a1;
            {  // self term: only edge-slot 0 contributes
                __half2 sv = *(const __half2*)(Hb + (size_t)snode * (F * 2) + cb);
                float2 f = __half22float2(sv);
                float gm = (es == 0) ? sw : 0.0f;
                a0 = gm * f.x; a1 = gm * f.y;
            }

            int len = end - start;
            if (len > 0) {
                int nbat = (len + 3) >> 2;
                auto ldep = [&](int b) -> int2 {  // clamp to end-1, zero weight
                    int p = start + b * 4 + es;
                    int q = (p < end) ? p : end - 1;
                    long long raw =
                        __builtin_nontemporal_load((const long long*)(ep + q));
                    int2 t;
                    t.x = (int)(unsigned)(raw & 0xffffffffLL);
                    t.y = (int)(raw >> 32);
                    if (p >= end) t.y = 0;
                    return t;
                };
                int2 e[UNC];
#pragma unroll
                for (int u = 0; u < UNC; u++) e[u] = ldep(u);
                for (int c0 = 0; c0 < nbat; c0 += UNC) {
                    __half2 v[UNC];
#pragma unroll
                    for (int u = 0; u < UNC; u++) {
                        unsigned off = (unsigned)e[u].x;  // src*256 byte offset
                        if (F == 64) off >>= 1;           // src*128
                        v[u] = *(const __half2*)(Hb + (off + cb));
                    }
                    int2 e2[UNC];  // prefetch next group's ep under consume
#pragma unroll
                    for (int u = 0; u < UNC; u++) e2[u] = ldep(c0 + UNC + u);
#pragma unroll
                    for (int u = 0; u < UNC; u++) {
                        float w = __int_as_float(e[u].y);
                        float2 f = __half22float2(v[u]);
                        a0 = fmaf(w, f.x, a0);
                        a1 = fmaf(w, f.y, a1);
                    }
#pragma unroll
                    for (int u = 0; u < UNC; u++) e[u] = e2[u];
                }
            }

            // reduce across the 4 edge slots (lanes fl, fl+16, fl+32, fl+48)
            a0 += __shfl_xor(a0, 16, 64); a1 += __shfl_xor(a1, 16, 64);
            a0 += __shfl_xor(a0, 32, 64); a1 += __shfl_xor(a1, 32, 64);

            if (es == 0) {  // lanes 0..15 write the 64B chunk
                float2 bv = *(const float2*)(bias + chunk * 32 + fl * 2);
                float o0 = a0 + bv.x, o1 = a1 + bv.y;
                if (RELU) { o0 = fmaxf(o0, 0.f); o1 = fmaxf(o1, 0.f); }
                if (OF16) {
                    union { __half2 h; unsigned u; } r;
                    r.h = __floats2half2_rn(o0, o1);
                    __builtin_nontemporal_store(
                        r.u, (unsigned*)((char*)outv + (size_t)snode * (F * 2) + cb));
                } else {
                    union { float2 f; long long ll; } r;
                    r.f = make_float2(o0, o1);
                    __builtin_nontemporal_store(
                        r.ll,
                        (long long*)((float*)outv + (size_t)snode * F + chunk * 32 + fl * 2));
                }
            }
        };

        int node = 0x7fffffff;
        if (lane == 0) node = atomicAdd(&ctr[chunk], 1);
        node = __shfl(node, 0, 64);
        while (node < n) {
            int nxtr = 0x7fffffff;
            if (lane == 0) nxtr = atomicAdd(&ctr[chunk], 1);  // overlaps process
            process(node);
            node = __shfl(nxtr, 0, 64);
        }
    }
}

// ---------- launch ----------

extern "C" void kernel_launch(void* const* d_in, const int* in_sizes, int n_in,
                              void* d_out, int out_size, void* d_ws, size_t ws_size,
                              hipStream_t stream) {
    const float* x   = (const float*)d_in[0];
    const int*   ei  = (const int*)d_in[1];   // int32 (JAX x64 disabled)
    const float* ew  = (const float*)d_in[2];
    const float* W1  = (const float*)d_in[3];
    const float* b1  = (const float*)d_in[4];
    const float* W2  = (const float*)d_in[5];
    const float* b2  = (const float*)d_in[6];
    const float* W3  = (const float*)d_in[7];
    const float* b3  = (const float*)d_in[8];
    float* out = (float*)d_out;

    const int N = in_sizes[0] / K_IN;
    const int E = in_sizes[2];
    const int* src = ei;
    const int* dst = ei + E;

    const int NB   = (N + 255) >> 8;     // buckets, <=256
    const int NBLK = (E + CE - 1) / CE;  // partition blocks
    const int M    = NB * NBLK;
    const int NBB  = (M + 255) / 256;
    const int NWT  = (2 * 128 * 128 + 64 * 128 + 1023) / 1024;  // wt_prep tail blocks
    const int VBLK = 1024;                                      // val tail blocks
    const int GAGG = 2048;                                      // persistent agg blocks

    char* w = (char*)d_ws;
    auto alloc = [&](size_t bytes) {
        void* p = (void*)w;
        w += (bytes + 255) & ~(size_t)255;
        return p;
    };
    int*            counts = (int*)alloc((size_t)M * 4);
    int*            base   = (int*)alloc((size_t)M * 4);
    int*            bsM    = (int*)alloc((size_t)NBB * 4);
    int*            boM    = (int*)alloc((size_t)NBB * 4);
    unsigned short* lrank  = (unsigned short*)alloc((size_t)E * 2);  // reused as rank2
    int2*           arr1   = (int2*)alloc((size_t)E * 8);
    float*          dinv   = (float*)alloc((size_t)N * 4);
    int*            row_ptr= (int*)alloc((size_t)(N + 1) * 4);
    int2*           ep     = (int2*)alloc((size_t)E * 8);
    _Float16*       Wt1    = (_Float16*)alloc(128 * 128 * 2);
    _Float16*       Wt2    = (_Float16*)alloc(128 * 128 * 2);
    _Float16*       Wt3    = (_Float16*)alloc(64 * 128 * 2);
    _Float16*       bufH   = (_Float16*)alloc((size_t)N * 128 * 2);  // gemm out
    _Float16*       bufX   = (_Float16*)alloc((size_t)N * 128 * 2);  // agg out (fp16)
    int*            ctr    = (int*)alloc(24 * 4);  // 3 agg dispatches x 8 counters

    int gGemm = (N + 63) / 64;

    // ---- CSR build (no global atomics) + fused W prep + ctr zero ----
    part_count_wt<<<NBLK + NWT, 1024, 0, stream>>>(dst, counts, lrank, NB, NBLK, E,
                                                   W1, W2, W3, Wt1, Wt2, Wt3, ctr);
    reduce_kernel<<<NBB, 256, 0, stream>>>(counts, bsM, M);
    scanb1024<<<1, 1024, 0, stream>>>(bsM, boM, NBB);
    scanw_kernel<<<NBB, 256, 0, stream>>>(counts, boM, base, M);
    part_scatter<<<NBLK, 1024, 0, stream>>>(src, dst, ew, base, lrank, arr1, NBLK, E);
    bucket_csr<<<NB, 1024, 0, stream>>>(arr1, base, lrank, dinv, row_ptr, ep,
                                        NB, NBLK, N, E);

    // ---- layers (gemm1 carries the fused val pass in tail blocks) ----
    mfma_gemm<128, false, true><<<gGemm + VBLK, 256, 0, stream>>>(
        x, Wt1, bufH, N, gGemm, VBLK, ep, dinv, row_ptr, E);
    agg_kernel<128, true, true><<<GAGG, 256, 0, stream>>>(
        (const __half*)bufH, row_ptr, ep, dinv, b1, bufX, ctr, N);
    mfma_gemm<128, true, false><<<gGemm, 256, 0, stream>>>(
        bufX, Wt2, bufH, N, gGemm, 0, nullptr, nullptr, nullptr, 0);
    agg_kernel<128, true, true><<<GAGG, 256, 0, stream>>>(
        (const __half*)bufH, row_ptr, ep, dinv, b2, bufX, ctr + 8, N);
    mfma_gemm<64, true, false><<<gGemm, 256, 0, stream>>>(
        bufX, Wt3, bufH, N, gGemm, 0, nullptr, nullptr, nullptr, 0);
    agg_kernel<64, false, false><<<GAGG, 256, 0, stream>>>(
        (const __half*)bufH, row_ptr, ep, dinv, b3, out, ctr + 16, N);
}

// Round 5
// 586.352 us; speedup vs baseline: 11.6003x; 11.6003x over previous
//
#include <hip/hip_runtime.h>
#include <hip/hip_bf16.h>
#include <hip/hip_fp16.h>

// GCN 3-layer. R14: chunk-contiguous H + resident-grid XCD pinning, no atomics.
// R13 post-mortem: per-node global atomic grab = ~27cy chip-serialized each ->
// 2.6ms. R12 post-mortem: blockIdx%8->XCD only holds for FULLY-RESIDENT grids
// (T1's verified regime). R14: H stored as H[chunk][node][32 fp16] (regions of
// N*64B = 3.2MB <= 4MB XCD L2, line-size-independent); agg is a persistent
// 2048-block grid (8 blk/CU, exactly resident), chunk = blockIdx % NCH, nodes
// statically strided (zero atomics). ep/out use nontemporal to not evict the
// resident H slice. Inner loop: 4 edge-slots x 16 lanes x half2, UNC=6 groups
// in flight, ep prefetched one group ahead. gemm epilogue/staging and val pass
// adapted to chunked layout (ep stores src*64). CSR build unchanged from R10.

#define K_IN 128              // all layers have in_features == 128
#define FIX_SCALE 8388608.0f  // 2^23 fixed point for ew sums
#define CE 4096               // edges per partition block (1024 thr x 4)

typedef _Float16 f16x8 __attribute__((ext_vector_type(8)));
typedef float f32x4 __attribute__((ext_vector_type(4)));

// ---------- pass 1: per-block bucket histogram + local rank (+W prep tail) ----------
__global__ __launch_bounds__(1024) void part_count_wt(
    const int* __restrict__ dst, int* __restrict__ counts,
    unsigned short* __restrict__ lrank, int nb, int nblk, int e,
    const float* __restrict__ W1, const float* __restrict__ W2,
    const float* __restrict__ W3, _Float16* __restrict__ Wt1,
    _Float16* __restrict__ Wt2, _Float16* __restrict__ Wt3) {
    int blk = blockIdx.x;
    if (blk >= nblk) {  // tail blocks: Wt[n][k] fp16 = W[k][n] fp32
        int i = (blk - nblk) * 1024 + threadIdx.x;
        if (i < 128 * 128) {
            int k = i >> 7, nn = i & 127;
            Wt1[(size_t)nn * 128 + k] = (_Float16)W1[i];
        } else if (i < 2 * 128 * 128) {
            int j = i - 128 * 128, k = j >> 7, nn = j & 127;
            Wt2[(size_t)nn * 128 + k] = (_Float16)W2[j];
        } else if (i < 2 * 128 * 128 + 64 * 128) {
            int l = i - 2 * 128 * 128, k = l >> 6, nn = l & 63;
            Wt3[(size_t)nn * 128 + k] = (_Float16)W3[l];
        }
        return;
    }
    __shared__ int c[256];  // nb <= 256
    int t = threadIdx.x;
    for (int i = t; i < nb; i += 1024) c[i] = 0;
    __syncthreads();
    int b0 = blk * CE;
#pragma unroll
    for (int j = 0; j < 4; j++) {
        int i = b0 + j * 1024 + t;
        if (i < e) {
            int b = dst[i] >> 8;
            int r = atomicAdd(&c[b], 1);  // LDS atomic
            lrank[i] = (unsigned short)r;
        }
    }
    __syncthreads();
    for (int i = t; i < nb; i += 1024) counts[(size_t)i * nblk + blk] = c[i];
}

// ---------- pass 2: parallel exclusive scan over counts[nb*nblk] ----------
__global__ __launch_bounds__(256) void reduce_kernel(const int* __restrict__ v,
                                                     int* __restrict__ bs, int m) {
    __shared__ int s[256];
    int t = threadIdx.x, i = blockIdx.x * 256 + t;
    s[t] = (i < m) ? v[i] : 0;
    __syncthreads();
    for (int off = 128; off > 0; off >>= 1) {
        if (t < off) s[t] += s[t + off];
        __syncthreads();
    }
    if (t == 0) bs[blockIdx.x] = s[0];
}

__global__ __launch_bounds__(1024) void scanb1024(const int* __restrict__ bs,
                                                  int* __restrict__ bo, int nbb) {
    __shared__ int s[1024];
    int t = threadIdx.x;
    s[t] = (t < nbb) ? bs[t] : 0;
    __syncthreads();
    for (int off = 1; off < 1024; off <<= 1) {
        int cur = s[t];
        int add = (t >= off) ? s[t - off] : 0;
        __syncthreads();
        s[t] = cur + add;
        __syncthreads();
    }
    if (t < nbb) bo[t] = (t == 0) ? 0 : s[t - 1];
}

__global__ __launch_bounds__(256) void scanw_kernel(const int* __restrict__ v,
                                                    const int* __restrict__ bo,
                                                    int* __restrict__ outp, int m) {
    __shared__ int s[256];
    int t = threadIdx.x, i = blockIdx.x * 256 + t;
    int c = (i < m) ? v[i] : 0;
    s[t] = c;
    __syncthreads();
    for (int off = 1; off < 256; off <<= 1) {
        int cur = s[t];
        int add = (t >= off) ? s[t - off] : 0;
        __syncthreads();
        s[t] = cur + add;
        __syncthreads();
    }
    if (i < m) outp[i] = bo[blockIdx.x] + (s[t] - c);  // exclusive
}

// ---------- pass 3: scatter into bucket-sorted order (packed src|dlow) ----------
__global__ __launch_bounds__(1024) void part_scatter(const int* __restrict__ src,
                                                     const int* __restrict__ dst,
                                                     const float* __restrict__ ew,
                                                     const int* __restrict__ base,
                                                     const unsigned short* __restrict__ lrank,
                                                     int2* __restrict__ arr1,
                                                     int nblk, int e) {
    int t = threadIdx.x, blk = blockIdx.x;
    int b0 = blk * CE;
#pragma unroll
    for (int j = 0; j < 4; j++) {
        int i = b0 + j * 1024 + t;
        if (i < e) {
            int d = dst[i];
            int b = d >> 8;
            int pos = base[(size_t)b * nblk + blk] + lrank[i];
            arr1[pos] = make_int2((src[i] << 8) | (d & 255), __float_as_int(ew[i]));
        }
    }
}

// ---------- pass 4: per-bucket CSR finalize (one 64-bit LDS atomic/edge) ----------
__global__ __launch_bounds__(1024) void bucket_csr(const int2* __restrict__ arr1,
                                                   const int* __restrict__ base,
                                                   unsigned short* __restrict__ rank2,
                                                   float* __restrict__ dinv,
                                                   int* __restrict__ row_ptr,
                                                   int2* __restrict__ ep,
                                                   int nb, int nblk, int n, int e) {
    __shared__ unsigned long long pk[256];  // cnt lo32 | fx-sum hi32
    __shared__ int nbase[256];
    __shared__ float ldsdinv[256];
    __shared__ int ss[256];
    int t = threadIdx.x, b = blockIdx.x;
    int beg = base[(size_t)b * nblk];
    int end = (b + 1 < nb) ? base[(size_t)(b + 1) * nblk] : e;
    if (t < 256) pk[t] = 0ULL;
    __syncthreads();
    for (int i = beg + t; i < end; i += 1024) {
        int2 a = arr1[i];
        int ld = a.x & 255;
        float w = __int_as_float(a.y);
        unsigned long long fx = (unsigned long long)(unsigned int)(w * FIX_SCALE + 0.5f);
        unsigned long long old = atomicAdd(&pk[ld], (fx << 32) | 1ULL);  // LDS, deterministic
        rank2[i] = (unsigned short)(old & 0xffffffffULL);
    }
    __syncthreads();
    int cnt = (t < 256) ? (int)(pk[t] & 0xffffffffULL) : 0;
    if (t < 256) ss[t] = cnt;
    __syncthreads();
    for (int off = 1; off < 256; off <<= 1) {
        int cur = 0, add = 0;
        if (t < 256) { cur = ss[t]; add = (t >= off) ? ss[t - off] : 0; }
        __syncthreads();
        if (t < 256) ss[t] = cur + add;
        __syncthreads();
    }
    if (t < 256) {
        nbase[t] = ss[t] - cnt;
        int d = b * 256 + t;
        if (d < n) {
            float dv = rsqrtf(1.0f + (float)(unsigned int)(pk[t] >> 32) * (1.0f / FIX_SCALE));
            dinv[d] = dv;
            ldsdinv[t] = dv;
            row_ptr[d] = beg + nbase[t];
        }
    }
    __syncthreads();
    for (int i = beg + t; i < end; i += 1024) {
        int2 a = arr1[i];
        int ld = a.x & 255;
        int pos = beg + nbase[ld] + rank2[i];
        float w = __int_as_float(a.y) * ldsdinv[ld];
        ep[pos] = make_int2(a.x >> 8, __float_as_int(w));  // src index, w*dinv[dst]
    }
}

// ---------- MFMA GEMM (+optional fused val pass in tail blocks) ----------
// H chunk-contiguous: H[c][node][32 fp16], region stride n*64B, c = col>>5.
// val: ep -> (src*64 byte offset within region, w*dinv[src]).
template <int NOUT, bool XF16, bool FUSEVAL>
__global__ __launch_bounds__(256) void mfma_gemm(const void* __restrict__ Xv,
                                                 const _Float16* __restrict__ Wt,
                                                 _Float16* __restrict__ H, int n,
                                                 int gGemm, int vblk,
                                                 int2* __restrict__ ep,
                                                 const float* __restrict__ dinv,
                                                 int* __restrict__ row_ptr, int e) {
    constexpr int CTW = NOUT / 64;  // col-tiles per wave: 2 (NOUT=128) / 1 (64)
    __shared__ _Float16 Xs[64][136];   // +8 pad: row stride 272B -> 2-way banks
    __shared__ _Float16 Ws[NOUT][136];
    int t = threadIdx.x;
    if (FUSEVAL && (int)blockIdx.x >= gGemm) {  // tail blocks: val pass
        int vb = blockIdx.x - gGemm;
        if (vb == 0 && t == 0) row_ptr[n] = e;
        for (int i = vb * 256 + t; i < e; i += vblk * 256) {
            int2 a = ep[i];
            float w = __int_as_float(a.y) * dinv[a.x];
            ep[i] = make_int2(a.x << 6, __float_as_int(w));  // src*64 (region offset)
        }
        return;
    }
    int row0 = blockIdx.x * 64;

    for (int i = t * 8; i < NOUT * K_IN; i += 2048) {
        int nn = i >> 7, k = i & 127;
        *(uint4*)&Ws[nn][k] = *(const uint4*)&Wt[i];
    }
    if (XF16) {
        const _Float16* X = (const _Float16*)Xv;  // chunked layout
        for (int i = t * 8; i < 64 * K_IN; i += 2048) {
            int r = i >> 7, k = i & 127;
            int row = row0 + r;
            uint4 v = make_uint4(0u, 0u, 0u, 0u);
            if (row < n)
                v = *(const uint4*)(X + ((size_t)(k >> 5) * n + row) * 32 + (k & 31));
            *(uint4*)&Xs[r][k] = v;
        }
    } else {
        const float* X = (const float*)Xv;  // fp32 row-major (layer-1 input)
        for (int i = t * 4; i < 64 * K_IN; i += 1024) {
            int r = i >> 7, k = i & 127;
            int row = row0 + r;
            float4 x4 = make_float4(0.f, 0.f, 0.f, 0.f);
            if (row < n) x4 = *(const float4*)(X + (size_t)row * K_IN + k);
            union { _Float16 h[4]; uint2 u; } uu;
            uu.h[0] = (_Float16)x4.x; uu.h[1] = (_Float16)x4.y;
            uu.h[2] = (_Float16)x4.z; uu.h[3] = (_Float16)x4.w;
            *(uint2*)&Xs[r][k] = uu.u;
        }
    }
    __syncthreads();

    int lane = t & 63, w = t >> 6;
    int m = lane & 15, g = lane >> 4;
    f32x4 acc[4][CTW];
#pragma unroll
    for (int mt = 0; mt < 4; mt++)
#pragma unroll
        for (int ct = 0; ct < CTW; ct++) acc[mt][ct] = (f32x4){0.f, 0.f, 0.f, 0.f};

#pragma unroll
    for (int kt = 0; kt < 4; kt++) {
        int kb = kt * 32 + g * 8;
        f16x8 a[4];
#pragma unroll
        for (int mt = 0; mt < 4; mt++) a[mt] = *(const f16x8*)&Xs[mt * 16 + m][kb];
#pragma unroll
        for (int ct = 0; ct < CTW; ct++) {
            int nn = w * (16 * CTW) + ct * 16 + m;
            f16x8 b = *(const f16x8*)&Ws[nn][kb];
#pragma unroll
            for (int mt = 0; mt < 4; mt++)
                acc[mt][ct] = __builtin_amdgcn_mfma_f32_16x16x32_f16(a[mt], b, acc[mt][ct], 0, 0, 0);
        }
    }

#pragma unroll
    for (int mt = 0; mt < 4; mt++) {
#pragma unroll
        for (int r = 0; r < 4; r++) {
            int row = row0 + mt * 16 + g * 4 + r;
            if (row < n) {
#pragma unroll
                for (int ct = 0; ct < CTW; ct++) {
                    int col = w * (16 * CTW) + ct * 16 + m;
                    H[((size_t)(col >> 5) * n + row) * 32 + (col & 31)] =
                        (_Float16)acc[mt][ct][r];
                }
            }
        }
    }
}

// ---------- aggregation: chunked H, resident-grid pinning, static split ----------
// Persistent 2048 blocks (8/CU, exactly resident -> blockIdx%8==XCD regime).
// chunk = blockIdx % NCH -> XCDs {c, c+4} gather only region c (3.2MB, L2-fit).
// Per wave: 1 node; 4 edge-slots x 16 lanes x half2; UNC=6 groups in flight;
// ep prefetched one group ahead (nontemporal); outputs nontemporal.
template <int F, bool RELU, bool OF16>
__global__ __launch_bounds__(256) void agg_kernel(const __half* __restrict__ H,
                                                  const int* __restrict__ row_ptr,
                                                  const int2* __restrict__ ep,
                                                  const float* __restrict__ dinv,
                                                  const float* __restrict__ bias,
                                                  void* __restrict__ outv, int n) {
    constexpr int NCH = F / 32;  // 64B feature chunks: 4 (F=128) / 2 (F=64)
    constexpr int UNC = 6;       // 4-edge gather groups in flight
    int wid = threadIdx.x >> 6;
    int lane = threadIdx.x & 63;
    int es = lane >> 4;   // edge slot 0..3
    int fl = lane & 15;   // half2 index within the 64B chunk
    int chunk = blockIdx.x % NCH;
    int rblk = blockIdx.x / NCH;
    int bpc = gridDim.x / NCH;  // blocks per chunk (grid % NCH == 0)
    int wstride = bpc * 4;
    const char* Hc = (const char*)H + (size_t)chunk * n * 64;  // region base
    const unsigned cfl = (unsigned)fl * 4u;
    float2 bv = *(const float2*)(bias + chunk * 32 + fl * 2);  // invariant

    for (int node = rblk * 4 + wid; node < n; node += wstride) {
        int start = __builtin_amdgcn_readfirstlane(row_ptr[node]);
        int end   = __builtin_amdgcn_readfirstlane(row_ptr[node + 1]);
        float di = dinv[node];
        float sw = di * di;

        float a0, a1;
        {  // self term: only edge-slot 0 contributes
            __half2 sv = *(const __half2*)(Hc + (size_t)node * 64 + cfl);
            float2 f = __half22float2(sv);
            float gm = (es == 0) ? sw : 0.0f;
            a0 = gm * f.x; a1 = gm * f.y;
        }

        int len = end - start;
        if (len > 0) {
            int nbat = (len + 3) >> 2;
            auto ldep = [&](int b) -> int2 {  // clamp to end-1, zero weight
                int p = start + b * 4 + es;
                int q = (p < end) ? p : end - 1;
                long long raw =
                    __builtin_nontemporal_load((const long long*)(ep + q));
                int2 t;
                t.x = (int)(unsigned)(raw & 0xffffffffLL);
                t.y = (int)(raw >> 32);
                if (p >= end) t.y = 0;
                return t;
            };
            int2 e[UNC];
#pragma unroll
            for (int u = 0; u < UNC; u++) e[u] = ldep(u);
            for (int c0 = 0; c0 < nbat; c0 += UNC) {
                __half2 v[UNC];
#pragma unroll
                for (int u = 0; u < UNC; u++) {
                    unsigned off = (unsigned)e[u].x;  // src*64 within region
                    v[u] = *(const __half2*)(Hc + (off + cfl));
                }
                int2 e2[UNC];  // prefetch next group's ep under consume
#pragma unroll
                for (int u = 0; u < UNC; u++) e2[u] = ldep(c0 + UNC + u);
#pragma unroll
                for (int u = 0; u < UNC; u++) {
                    float w = __int_as_float(e[u].y);
                    float2 f = __half22float2(v[u]);
                    a0 = fmaf(w, f.x, a0);
                    a1 = fmaf(w, f.y, a1);
                }
#pragma unroll
                for (int u = 0; u < UNC; u++) e[u] = e2[u];
            }
        }

        // reduce across the 4 edge slots (lanes fl, fl+16, fl+32, fl+48)
        a0 += __shfl_xor(a0, 16, 64); a1 += __shfl_xor(a1, 16, 64);
        a0 += __shfl_xor(a0, 32, 64); a1 += __shfl_xor(a1, 32, 64);

        if (es == 0) {  // lanes 0..15 write this chunk's 64B
            float o0 = a0 + bv.x, o1 = a1 + bv.y;
            if (RELU) { o0 = fmaxf(o0, 0.f); o1 = fmaxf(o1, 0.f); }
            if (OF16) {  // chunked fp16 out (next layer's gemm input)
                union { __half2 h; unsigned u; } r;
                r.h = __floats2half2_rn(o0, o1);
                __builtin_nontemporal_store(
                    r.u, (unsigned*)((char*)outv + (size_t)chunk * n * 64 +
                                     (size_t)node * 64 + cfl));
            } else {  // final layer: row-major fp32
                union { float2 f; long long ll; } r;
                r.f = make_float2(o0, o1);
                __builtin_nontemporal_store(
                    r.ll,
                    (long long*)((float*)outv + (size_t)node * F + chunk * 32 + fl * 2));
            }
        }
    }
}

// ---------- launch ----------

extern "C" void kernel_launch(void* const* d_in, const int* in_sizes, int n_in,
                              void* d_out, int out_size, void* d_ws, size_t ws_size,
                              hipStream_t stream) {
    const float* x   = (const float*)d_in[0];
    const int*   ei  = (const int*)d_in[1];   // int32 (JAX x64 disabled)
    const float* ew  = (const float*)d_in[2];
    const float* W1  = (const float*)d_in[3];
    const float* b1  = (const float*)d_in[4];
    const float* W2  = (const float*)d_in[5];
    const float* b2  = (const float*)d_in[6];
    const float* W3  = (const float*)d_in[7];
    const float* b3  = (const float*)d_in[8];
    float* out = (float*)d_out;

    const int N = in_sizes[0] / K_IN;
    const int E = in_sizes[2];
    const int* src = ei;
    const int* dst = ei + E;

    const int NB   = (N + 255) >> 8;     // buckets, <=256
    const int NBLK = (E + CE - 1) / CE;  // partition blocks
    const int M    = NB * NBLK;
    const int NBB  = (M + 255) / 256;
    const int NWT  = (2 * 128 * 128 + 64 * 128 + 1023) / 1024;  // wt_prep tail blocks
    const int VBLK = 1024;                                      // val tail blocks
    const int GAGG = 2048;                                      // persistent agg blocks

    char* w = (char*)d_ws;
    auto alloc = [&](size_t bytes) {
        void* p = (void*)w;
        w += (bytes + 255) & ~(size_t)255;
        return p;
    };
    int*            counts = (int*)alloc((size_t)M * 4);
    int*            base   = (int*)alloc((size_t)M * 4);
    int*            bsM    = (int*)alloc((size_t)NBB * 4);
    int*            boM    = (int*)alloc((size_t)NBB * 4);
    unsigned short* lrank  = (unsigned short*)alloc((size_t)E * 2);  // reused as rank2
    int2*           arr1   = (int2*)alloc((size_t)E * 8);
    float*          dinv   = (float*)alloc((size_t)N * 4);
    int*            row_ptr= (int*)alloc((size_t)(N + 1) * 4);
    int2*           ep     = (int2*)alloc((size_t)E * 8);
    _Float16*       Wt1    = (_Float16*)alloc(128 * 128 * 2);
    _Float16*       Wt2    = (_Float16*)alloc(128 * 128 * 2);
    _Float16*       Wt3    = (_Float16*)alloc(64 * 128 * 2);
    _Float16*       bufH   = (_Float16*)alloc((size_t)N * 128 * 2);  // gemm out (chunked)
    _Float16*       bufX   = (_Float16*)alloc((size_t)N * 128 * 2);  // agg out (chunked)

    int gGemm = (N + 63) / 64;

    // ---- CSR build (no global atomics) + fused W prep ----
    part_count_wt<<<NBLK + NWT, 1024, 0, stream>>>(dst, counts, lrank, NB, NBLK, E,
                                                   W1, W2, W3, Wt1, Wt2, Wt3);
    reduce_kernel<<<NBB, 256, 0, stream>>>(counts, bsM, M);
    scanb1024<<<1, 1024, 0, stream>>>(bsM, boM, NBB);
    scanw_kernel<<<NBB, 256, 0, stream>>>(counts, boM, base, M);
    part_scatter<<<NBLK, 1024, 0, stream>>>(src, dst, ew, base, lrank, arr1, NBLK, E);
    bucket_csr<<<NB, 1024, 0, stream>>>(arr1, base, lrank, dinv, row_ptr, ep,
                                        NB, NBLK, N, E);

    // ---- layers (gemm1 carries the fused val pass in tail blocks) ----
    mfma_gemm<128, false, true><<<gGemm + VBLK, 256, 0, stream>>>(
        x, Wt1, bufH, N, gGemm, VBLK, ep, dinv, row_ptr, E);
    agg_kernel<128, true, true><<<GAGG, 256, 0, stream>>>(
        (const __half*)bufH, row_ptr, ep, dinv, b1, bufX, N);
    mfma_gemm<128, true, false><<<gGemm, 256, 0, stream>>>(
        bufX, Wt2, bufH, N, gGemm, 0, nullptr, nullptr, nullptr, 0);
    agg_kernel<128, true, true><<<GAGG, 256, 0, stream>>>(
        (const __half*)bufH, row_ptr, ep, dinv, b2, bufX, N);
    mfma_gemm<64, true, false><<<gGemm, 256, 0, stream>>>(
        bufX, Wt3, bufH, N, gGemm, 0, nullptr, nullptr, nullptr, 0);
    agg_kernel<64, false, false><<<GAGG, 256, 0, stream>>>(
        (const __half*)bufH, row_ptr, ep, dinv, b3, out, N);
}

// Round 6
// 293.989 us; speedup vs baseline: 23.1364x; 1.9945x over previous
//
#include <hip/hip_runtime.h>
#include <hip/hip_bf16.h>
#include <hip/hip_fp16.h>

// GCN 3-layer. R15: agg reverted to R10 exact form (proven 48us; at its
// queue(128 slots)x latency(~550cy L3) bound — R11-R14 established that every
// latency-cutting restructure inflates VALU past the memory bound). New in
// R15: CSR-build scattered-write fix. part_scatter and bucket_csr both emit
// 1.6M x 8B partial-line scattered stores (write-allocate line fills, cross-
// XCD partial-dirty lines). Both kernels now stage the block's edges in LDS
// in output order (block-local counting sort / bucket-local rank order) and
// sweep out linearly -> coalesced streaming writes. Everything else = R10.

#define K_IN 128              // all layers have in_features == 128
#define FIX_SCALE 8388608.0f  // 2^23 fixed point for ew sums
#define CE 4096               // edges per partition block (1024 thr x 4)

typedef _Float16 f16x8 __attribute__((ext_vector_type(8)));
typedef float f32x4 __attribute__((ext_vector_type(4)));

// ---------- pass 1: per-block bucket histogram + local rank (+W prep tail) ----------
__global__ __launch_bounds__(1024) void part_count_wt(
    const int* __restrict__ dst, int* __restrict__ counts,
    unsigned short* __restrict__ lrank, int nb, int nblk, int e,
    const float* __restrict__ W1, const float* __restrict__ W2,
    const float* __restrict__ W3, _Float16* __restrict__ Wt1,
    _Float16* __restrict__ Wt2, _Float16* __restrict__ Wt3) {
    int blk = blockIdx.x;
    if (blk >= nblk) {  // tail blocks: Wt[n][k] fp16 = W[k][n] fp32
        int i = (blk - nblk) * 1024 + threadIdx.x;
        if (i < 128 * 128) {
            int k = i >> 7, nn = i & 127;
            Wt1[(size_t)nn * 128 + k] = (_Float16)W1[i];
        } else if (i < 2 * 128 * 128) {
            int j = i - 128 * 128, k = j >> 7, nn = j & 127;
            Wt2[(size_t)nn * 128 + k] = (_Float16)W2[j];
        } else if (i < 2 * 128 * 128 + 64 * 128) {
            int l = i - 2 * 128 * 128, k = l >> 6, nn = l & 63;
            Wt3[(size_t)nn * 128 + k] = (_Float16)W3[l];
        }
        return;
    }
    __shared__ int c[256];  // nb <= 256
    int t = threadIdx.x;
    for (int i = t; i < nb; i += 1024) c[i] = 0;
    __syncthreads();
    int b0 = blk * CE;
#pragma unroll
    for (int j = 0; j < 4; j++) {
        int i = b0 + j * 1024 + t;
        if (i < e) {
            int b = dst[i] >> 8;
            int r = atomicAdd(&c[b], 1);  // LDS atomic
            lrank[i] = (unsigned short)r;
        }
    }
    __syncthreads();
    for (int i = t; i < nb; i += 1024) counts[(size_t)i * nblk + blk] = c[i];
}

// ---------- pass 2: parallel exclusive scan over counts[nb*nblk] ----------
__global__ __launch_bounds__(256) void reduce_kernel(const int* __restrict__ v,
                                                     int* __restrict__ bs, int m) {
    __shared__ int s[256];
    int t = threadIdx.x, i = blockIdx.x * 256 + t;
    s[t] = (i < m) ? v[i] : 0;
    __syncthreads();
    for (int off = 128; off > 0; off >>= 1) {
        if (t < off) s[t] += s[t + off];
        __syncthreads();
    }
    if (t == 0) bs[blockIdx.x] = s[0];
}

__global__ __launch_bounds__(1024) void scanb1024(const int* __restrict__ bs,
                                                  int* __restrict__ bo, int nbb) {
    __shared__ int s[1024];
    int t = threadIdx.x;
    s[t] = (t < nbb) ? bs[t] : 0;
    __syncthreads();
    for (int off = 1; off < 1024; off <<= 1) {
        int cur = s[t];
        int add = (t >= off) ? s[t - off] : 0;
        __syncthreads();
        s[t] = cur + add;
        __syncthreads();
    }
    if (t < nbb) bo[t] = (t == 0) ? 0 : s[t - 1];
}

__global__ __launch_bounds__(256) void scanw_kernel(const int* __restrict__ v,
                                                    const int* __restrict__ bo,
                                                    int* __restrict__ outp, int m) {
    __shared__ int s[256];
    int t = threadIdx.x, i = blockIdx.x * 256 + t;
    int c = (i < m) ? v[i] : 0;
    s[t] = c;
    __syncthreads();
    for (int off = 1; off < 256; off <<= 1) {
        int cur = s[t];
        int add = (t >= off) ? s[t - off] : 0;
        __syncthreads();
        s[t] = cur + add;
        __syncthreads();
    }
    if (i < m) outp[i] = bo[blockIdx.x] + (s[t] - c);  // exclusive
}

// ---------- pass 3: scatter into bucket-sorted order, LDS-staged ----------
// Block-local counting sort: place edges in LDS at lbase[b]+lrank (dense
// [0,nloc)), then sweep out linearly. Output addr of slot s is gb[bb[s]]+s
// where gb[b] = base[b*nblk+blk]-lbase[b] -> per-bucket runs are contiguous
// -> coalesced streaming stores instead of 8B scattered write-allocates.
__global__ __launch_bounds__(1024) void part_scatter(const int* __restrict__ src,
                                                     const int* __restrict__ dst,
                                                     const float* __restrict__ ew,
                                                     const int* __restrict__ base,
                                                     const int* __restrict__ counts,
                                                     const unsigned short* __restrict__ lrank,
                                                     int2* __restrict__ arr1,
                                                     int nb, int nblk, int e) {
    __shared__ int hs[256];            // inclusive scan of block histogram
    __shared__ int lbase[256];         // exclusive
    __shared__ int gb[256];            // global base minus local base
    __shared__ unsigned char bb[CE];   // bucket of each LDS slot
    __shared__ int2 buf[CE];           // 32KB staged edges
    int t = threadIdx.x, blk = blockIdx.x;

    if (t < 256) hs[t] = (t < nb) ? counts[(size_t)t * nblk + blk] : 0;
    __syncthreads();
    for (int off = 1; off < 256; off <<= 1) {
        int cur = 0, add = 0;
        if (t < 256) { cur = hs[t]; add = (t >= off) ? hs[t - off] : 0; }
        __syncthreads();
        if (t < 256) hs[t] = cur + add;
        __syncthreads();
    }
    if (t < 256) {
        int cnt = (t < nb) ? counts[(size_t)t * nblk + blk] : 0;
        int lb = hs[t] - cnt;
        lbase[t] = lb;
        gb[t] = ((t < nb) ? base[(size_t)t * nblk + blk] : 0) - lb;
    }
    __syncthreads();

    int b0 = blk * CE;
    int nloc = e - b0; if (nloc > CE) nloc = CE;
#pragma unroll
    for (int j = 0; j < 4; j++) {
        int i = b0 + j * 1024 + t;
        if (i < e) {
            int d = dst[i];
            int b = d >> 8;
            int slot = lbase[b] + lrank[i];
            buf[slot] = make_int2((src[i] << 8) | (d & 255), __float_as_int(ew[i]));
            bb[slot] = (unsigned char)b;
        }
    }
    __syncthreads();
#pragma unroll
    for (int j = 0; j < 4; j++) {
        int s = j * 1024 + t;
        if (s < nloc) arr1[gb[bb[s]] + s] = buf[s];
    }
}

// ---------- pass 4: per-bucket CSR finalize, LDS-staged ep writes ----------
#define EPCAP 10240  // LDS staging slots (expected max bucket ~8.6K)
__global__ __launch_bounds__(1024) void bucket_csr(const int2* __restrict__ arr1,
                                                   const int* __restrict__ base,
                                                   unsigned short* __restrict__ rank2,
                                                   float* __restrict__ dinv,
                                                   int* __restrict__ row_ptr,
                                                   int2* __restrict__ ep,
                                                   int nb, int nblk, int n, int e) {
    __shared__ unsigned long long pk[256];  // cnt lo32 | fx-sum hi32
    __shared__ int nbase[256];
    __shared__ float ldsdinv[256];
    __shared__ int ss[256];
    __shared__ int2 eps[EPCAP];             // 80KB staging
    int t = threadIdx.x, b = blockIdx.x;
    int beg = base[(size_t)b * nblk];
    int end = (b + 1 < nb) ? base[(size_t)(b + 1) * nblk] : e;
    if (t < 256) pk[t] = 0ULL;
    __syncthreads();
    for (int i = beg + t; i < end; i += 1024) {
        int2 a = arr1[i];
        int ld = a.x & 255;
        float w = __int_as_float(a.y);
        unsigned long long fx = (unsigned long long)(unsigned int)(w * FIX_SCALE + 0.5f);
        unsigned long long old = atomicAdd(&pk[ld], (fx << 32) | 1ULL);  // LDS, deterministic
        rank2[i] = (unsigned short)(old & 0xffffffffULL);
    }
    __syncthreads();
    int cnt = (t < 256) ? (int)(pk[t] & 0xffffffffULL) : 0;
    if (t < 256) ss[t] = cnt;
    __syncthreads();
    for (int off = 1; off < 256; off <<= 1) {
        int cur = 0, add = 0;
        if (t < 256) { cur = ss[t]; add = (t >= off) ? ss[t - off] : 0; }
        __syncthreads();
        if (t < 256) ss[t] = cur + add;
        __syncthreads();
    }
    if (t < 256) {
        nbase[t] = ss[t] - cnt;
        int d = b * 256 + t;
        if (d < n) {
            float dv = rsqrtf(1.0f + (float)(unsigned int)(pk[t] >> 32) * (1.0f / FIX_SCALE));
            dinv[d] = dv;
            ldsdinv[t] = dv;
            row_ptr[d] = beg + nbase[t];
        }
    }
    __syncthreads();
    int tot = end - beg;
    if (tot <= EPCAP) {  // stage in sorted order, then stream out (coalesced)
        for (int i = beg + t; i < end; i += 1024) {
            int2 a = arr1[i];
            int ld = a.x & 255;
            float w = __int_as_float(a.y) * ldsdinv[ld];
            eps[nbase[ld] + rank2[i]] = make_int2(a.x >> 8, __float_as_int(w));
        }
        __syncthreads();
        for (int j = t; j < tot; j += 1024) ep[beg + j] = eps[j];
    } else {  // fallback: direct scattered writes (correct for any bucket size)
        for (int i = beg + t; i < end; i += 1024) {
            int2 a = arr1[i];
            int ld = a.x & 255;
            int pos = beg + nbase[ld] + rank2[i];
            float w = __int_as_float(a.y) * ldsdinv[ld];
            ep[pos] = make_int2(a.x >> 8, __float_as_int(w));
        }
    }
}

// ---------- MFMA GEMM (+optional fused val pass in tail blocks) ----------
// H[n x NOUT](fp16) = X[n x 128] @ W. val: ep -> (src*256 byte off, w*dinv[src]).
template <int NOUT, bool XF16, bool FUSEVAL>
__global__ __launch_bounds__(256) void mfma_gemm(const void* __restrict__ Xv,
                                                 const _Float16* __restrict__ Wt,
                                                 _Float16* __restrict__ H, int n,
                                                 int gGemm, int vblk,
                                                 int2* __restrict__ ep,
                                                 const float* __restrict__ dinv,
                                                 int* __restrict__ row_ptr, int e) {
    constexpr int CTW = NOUT / 64;  // col-tiles per wave: 2 (NOUT=128) / 1 (64)
    __shared__ _Float16 Xs[64][136];   // +8 pad: row stride 272B -> 2-way banks
    __shared__ _Float16 Ws[NOUT][136];
    int t = threadIdx.x;
    if (FUSEVAL && (int)blockIdx.x >= gGemm) {  // tail blocks: val pass
        int vb = blockIdx.x - gGemm;
        if (vb == 0 && t == 0) row_ptr[n] = e;
        for (int i = vb * 256 + t; i < e; i += vblk * 256) {
            int2 a = ep[i];
            float w = __int_as_float(a.y) * dinv[a.x];
            ep[i] = make_int2(a.x << 8, __float_as_int(w));  // byte off (fp16 row F=128)
        }
        return;
    }
    int row0 = blockIdx.x * 64;

    for (int i = t * 8; i < NOUT * K_IN; i += 2048) {
        int nn = i >> 7, k = i & 127;
        *(uint4*)&Ws[nn][k] = *(const uint4*)&Wt[i];
    }
    if (XF16) {
        const _Float16* X = (const _Float16*)Xv;
        for (int i = t * 8; i < 64 * K_IN; i += 2048) {
            int r = i >> 7, k = i & 127;
            int row = row0 + r;
            uint4 v = make_uint4(0u, 0u, 0u, 0u);
            if (row < n) v = *(const uint4*)(X + (size_t)row * K_IN + k);
            *(uint4*)&Xs[r][k] = v;
        }
    } else {
        const float* X = (const float*)Xv;
        for (int i = t * 4; i < 64 * K_IN; i += 1024) {
            int r = i >> 7, k = i & 127;
            int row = row0 + r;
            float4 x4 = make_float4(0.f, 0.f, 0.f, 0.f);
            if (row < n) x4 = *(const float4*)(X + (size_t)row * K_IN + k);
            union { _Float16 h[4]; uint2 u; } uu;
            uu.h[0] = (_Float16)x4.x; uu.h[1] = (_Float16)x4.y;
            uu.h[2] = (_Float16)x4.z; uu.h[3] = (_Float16)x4.w;
            *(uint2*)&Xs[r][k] = uu.u;
        }
    }
    __syncthreads();

    int lane = t & 63, w = t >> 6;
    int m = lane & 15, g = lane >> 4;
    f32x4 acc[4][CTW];
#pragma unroll
    for (int mt = 0; mt < 4; mt++)
#pragma unroll
        for (int ct = 0; ct < CTW; ct++) acc[mt][ct] = (f32x4){0.f, 0.f, 0.f, 0.f};

#pragma unroll
    for (int kt = 0; kt < 4; kt++) {
        int kb = kt * 32 + g * 8;
        f16x8 a[4];
#pragma unroll
        for (int mt = 0; mt < 4; mt++) a[mt] = *(const f16x8*)&Xs[mt * 16 + m][kb];
#pragma unroll
        for (int ct = 0; ct < CTW; ct++) {
            int nn = w * (16 * CTW) + ct * 16 + m;
            f16x8 b = *(const f16x8*)&Ws[nn][kb];
#pragma unroll
            for (int mt = 0; mt < 4; mt++)
                acc[mt][ct] = __builtin_amdgcn_mfma_f32_16x16x32_f16(a[mt], b, acc[mt][ct], 0, 0, 0);
        }
    }

#pragma unroll
    for (int mt = 0; mt < 4; mt++) {
#pragma unroll
        for (int r = 0; r < 4; r++) {
            int row = row0 + mt * 16 + g * 4 + r;
            if (row < n) {
#pragma unroll
                for (int ct = 0; ct < CTW; ct++)
                    H[(size_t)row * NOUT + w * (16 * CTW) + ct * 16 + m] =
                        (_Float16)acc[mt][ct][r];
            }
        }
    }
}

// ---------- aggregation: scalar ep loads, 1-VALU-add gathers, fp32 accum ----------
template <int F, bool RELU, bool OF16>
__global__ __launch_bounds__(256) void agg_kernel(const __half* __restrict__ H,
                                                  const int* __restrict__ row_ptr,
                                                  const int2* __restrict__ ep,
                                                  const float* __restrict__ dinv,
                                                  const float* __restrict__ bias,
                                                  void* __restrict__ outv, int n) {
    constexpr int UN = 24;
    int wid = threadIdx.x >> 6;
    int lane = threadIdx.x & 63;
    int node = blockIdx.x * 4 + wid;
    if (node >= n) return;

    int start = __builtin_amdgcn_readfirstlane(row_ptr[node]);
    int end   = __builtin_amdgcn_readfirstlane(row_ptr[node + 1]);
    float di = dinv[node];
    float sw = di * di;

    const unsigned lb = (unsigned)lane * (F == 128 ? 4u : 2u);  // lane byte offset

    float a0, a1;
    if (F == 128) {
        float2 s2 = __half22float2(((const __half2*)(H + (size_t)node * 128))[lane]);
        a0 = s2.x * sw; a1 = s2.y * sw;
    } else {
        a0 = __half2float(H[(size_t)node * 64 + lane]) * sw; a1 = 0.f;
    }

    int len = end - start;
    int nf = len / UN;
    for (int b = 0; b < nf; b++) {
        int p0 = start + b * UN;
        int2 e[UN];
#pragma unroll
        for (int u = 0; u < UN; u++) e[u] = ep[p0 + u];  // uniform addr -> s_load
        __half2 v2[UN];
        __half v1[UN];
#pragma unroll
        for (int u = 0; u < UN; u++) {
            unsigned off = (unsigned)e[u].x;
            if (F == 64) off >>= 1;
            if (F == 128) v2[u] = *(const __half2*)((const char*)H + (off + lb));
            else          v1[u] = *(const __half*)((const char*)H + (off + lb));
        }
#pragma unroll
        for (int u = 0; u < UN; u++) {
            float w = __int_as_float(e[u].y);
            if (F == 128) {
                float2 f = __half22float2(v2[u]);
                a0 += w * f.x; a1 += w * f.y;
            } else {
                a0 += w * __half2float(v1[u]);
            }
        }
    }
    int base = start + nf * UN;
    if (base < end) {  // single predicated tail batch (uniform predicates)
        int2 e[UN];
#pragma unroll
        for (int u = 0; u < UN; u++) {
            int p = base + u;
            int q = (p < end) ? p : end - 1;
            int2 t2 = ep[q];
            if (p >= end) t2.y = 0;
            e[u] = t2;
        }
        __half2 v2[UN];
        __half v1[UN];
#pragma unroll
        for (int u = 0; u < UN; u++) {
            unsigned off = (unsigned)e[u].x;
            if (F == 64) off >>= 1;
            if (F == 128) v2[u] = *(const __half2*)((const char*)H + (off + lb));
            else          v1[u] = *(const __half*)((const char*)H + (off + lb));
        }
#pragma unroll
        for (int u = 0; u < UN; u++) {
            float w = __int_as_float(e[u].y);
            if (F == 128) {
                float2 f = __half22float2(v2[u]);
                a0 += w * f.x; a1 += w * f.y;
            } else {
                a0 += w * __half2float(v1[u]);
            }
        }
    }

    if (F == 128) {
        float o0 = a0 + bias[lane * 2];
        float o1 = a1 + bias[lane * 2 + 1];
        if (RELU) { o0 = fmaxf(o0, 0.f); o1 = fmaxf(o1, 0.f); }
        if (OF16) {
            ((__half2*)outv)[(size_t)node * 64 + lane] = __floats2half2_rn(o0, o1);
        } else {
            *(float2*)((float*)outv + (size_t)node * 128 + lane * 2) = make_float2(o0, o1);
        }
    } else {
        float o = a0 + bias[lane];
        if (RELU) o = fmaxf(o, 0.f);
        if (OF16) ((__half*)outv)[(size_t)node * 64 + lane] = __float2half(o);
        else      ((float*)outv)[(size_t)node * 64 + lane] = o;
    }
}

// ---------- launch ----------

extern "C" void kernel_launch(void* const* d_in, const int* in_sizes, int n_in,
                              void* d_out, int out_size, void* d_ws, size_t ws_size,
                              hipStream_t stream) {
    const float* x   = (const float*)d_in[0];
    const int*   ei  = (const int*)d_in[1];   // int32 (JAX x64 disabled)
    const float* ew  = (const float*)d_in[2];
    const float* W1  = (const float*)d_in[3];
    const float* b1  = (const float*)d_in[4];
    const float* W2  = (const float*)d_in[5];
    const float* b2  = (const float*)d_in[6];
    const float* W3  = (const float*)d_in[7];
    const float* b3  = (const float*)d_in[8];
    float* out = (float*)d_out;

    const int N = in_sizes[0] / K_IN;
    const int E = in_sizes[2];
    const int* src = ei;
    const int* dst = ei + E;

    const int NB   = (N + 255) >> 8;     // buckets, <=256
    const int NBLK = (E + CE - 1) / CE;  // partition blocks
    const int M    = NB * NBLK;
    const int NBB  = (M + 255) / 256;
    const int NWT  = (2 * 128 * 128 + 64 * 128 + 1023) / 1024;  // wt_prep tail blocks
    const int VBLK = 1024;                                      // val tail blocks

    char* w = (char*)d_ws;
    auto alloc = [&](size_t bytes) {
        void* p = (void*)w;
        w += (bytes + 255) & ~(size_t)255;
        return p;
    };
    int*            counts = (int*)alloc((size_t)M * 4);
    int*            base   = (int*)alloc((size_t)M * 4);
    int*            bsM    = (int*)alloc((size_t)NBB * 4);
    int*            boM    = (int*)alloc((size_t)NBB * 4);
    unsigned short* lrank  = (unsigned short*)alloc((size_t)E * 2);  // reused as rank2
    int2*           arr1   = (int2*)alloc((size_t)E * 8);
    float*          dinv   = (float*)alloc((size_t)N * 4);
    int*            row_ptr= (int*)alloc((size_t)(N + 1) * 4);
    int2*           ep     = (int2*)alloc((size_t)E * 8);
    _Float16*       Wt1    = (_Float16*)alloc(128 * 128 * 2);
    _Float16*       Wt2    = (_Float16*)alloc(128 * 128 * 2);
    _Float16*       Wt3    = (_Float16*)alloc(64 * 128 * 2);
    _Float16*       bufH   = (_Float16*)alloc((size_t)N * 128 * 2);  // gemm out
    _Float16*       bufX   = (_Float16*)alloc((size_t)N * 128 * 2);  // agg out (fp16)

    int gGemm = (N + 63) / 64;
    int gAgg  = (N + 3) / 4;

    // ---- CSR build (no global atomics) + fused W prep ----
    part_count_wt<<<NBLK + NWT, 1024, 0, stream>>>(dst, counts, lrank, NB, NBLK, E,
                                                   W1, W2, W3, Wt1, Wt2, Wt3);
    reduce_kernel<<<NBB, 256, 0, stream>>>(counts, bsM, M);
    scanb1024<<<1, 1024, 0, stream>>>(bsM, boM, NBB);
    scanw_kernel<<<NBB, 256, 0, stream>>>(counts, boM, base, M);
    part_scatter<<<NBLK, 1024, 0, stream>>>(src, dst, ew, base, counts, lrank,
                                            arr1, NB, NBLK, E);
    bucket_csr<<<NB, 1024, 0, stream>>>(arr1, base, lrank, dinv, row_ptr, ep,
                                        NB, NBLK, N, E);

    // ---- layers (gemm1 carries the fused val pass in tail blocks) ----
    mfma_gemm<128, false, true><<<gGemm + VBLK, 256, 0, stream>>>(
        x, Wt1, bufH, N, gGemm, VBLK, ep, dinv, row_ptr, E);
    agg_kernel<128, true, true><<<gAgg, 256, 0, stream>>>((const __half*)bufH, row_ptr, ep,
                                                          dinv, b1, bufX, N);
    mfma_gemm<128, true, false><<<gGemm, 256, 0, stream>>>(
        bufX, Wt2, bufH, N, gGemm, 0, nullptr, nullptr, nullptr, 0);
    agg_kernel<128, true, true><<<gAgg, 256, 0, stream>>>((const __half*)bufH, row_ptr, ep,
                                                          dinv, b2, bufX, N);
    mfma_gemm<64, true, false><<<gGemm, 256, 0, stream>>>(
        bufX, Wt3, bufH, N, gGemm, 0, nullptr, nullptr, nullptr, 0);
    agg_kernel<64, false, false><<<gAgg, 256, 0, stream>>>((const __half*)bufH, row_ptr, ep,
                                                           dinv, b3, out, N);
}